// Round 1
// baseline (268.238 us; speedup 1.0000x reference)
//
#include <hip/hip_runtime.h>

// BasisEncoder: out[b, :] = one_hot(x[b] % 64, 64) as fp32.
// (x % 256) % 64 == x % 64 because 64 divides 256; x >= 0 so & 63 is exact.
//
// Layout: out is row-major [B, 64] fp32 = [B, 16] float4.
// One float4 store per thread; 16 consecutive threads cover one row,
// so stores are fully coalesced (16 B/lane). x[row] load is a broadcast
// within each 16-lane group.

#define BATCH (1048576)
#define VEC_PER_ROW 16            // 64 floats / 4
#define TOTAL_VEC (BATCH * VEC_PER_ROW)

__global__ __launch_bounds__(256) void basis_encoder_kernel(
    const int* __restrict__ x, float4* __restrict__ out) {
  int gid = blockIdx.x * blockDim.x + threadIdx.x;  // [0, TOTAL_VEC)
  int row = gid >> 4;
  int chunk = gid & 15;          // which group of 4 columns
  unsigned idx = (unsigned)x[row] & 63u;
  int base = chunk << 2;         // first column of this chunk
  float4 v;
  v.x = (idx == (unsigned)(base + 0)) ? 1.0f : 0.0f;
  v.y = (idx == (unsigned)(base + 1)) ? 1.0f : 0.0f;
  v.z = (idx == (unsigned)(base + 2)) ? 1.0f : 0.0f;
  v.w = (idx == (unsigned)(base + 3)) ? 1.0f : 0.0f;
  out[gid] = v;
}

extern "C" void kernel_launch(void* const* d_in, const int* in_sizes, int n_in,
                              void* d_out, int out_size, void* d_ws, size_t ws_size,
                              hipStream_t stream) {
  const int* x = (const int*)d_in[0];
  float4* out = (float4*)d_out;
  // TOTAL_VEC = 16M threads; 256/block -> 65536 blocks.
  basis_encoder_kernel<<<TOTAL_VEC / 256, 256, 0, stream>>>(x, out);
}